// Round 4
// baseline (187.968 us; speedup 1.0000x reference)
//
#include <hip/hip_runtime.h>
#include <hip/hip_bf16.h>

// FiLM block, MI355X. I/O fp32; compute bf16 MFMA (A=weights, B=tokens,
// C col=token), fp32 accum. R10 = R8 (passed, 100.2us) + the two fixes the
// R8 counters demanded, with ROCm-7.2-valid conversion API:
//  (1) __launch_bounds__(1024, 4): R8's bare (1024) made the compiler cap
//      VGPR at 64 (8-waves/SIMD target) while live state is ~110 regs ->
//      scratch spills in the hot loop. LDS (127.2 KB) caps us at 1
//      block/CU = 4 waves/SIMD anyway, which permits 128 VGPRs.
//  (2) VALU diet in film_main's hot paths: leaky folded in-place into acc,
//      float->bf16 via scalar __float2bfloat16 casts (compiler packs
//      adjacent pairs into v_cvt_pk_bf16_f32; replaces the 4-5 op integer
//      RNE f2b), leaky via fmaxf(t, 0.01t) (== branchy form, finite t),
//      normalize as fma(v, rs, -mu*rs). No inline asm.
// prep is byte-identical to R8 (cold path; weight bits unchanged).
// XCD swizzle kept: bid = q*128 + o*8 + c -> the 16 o-blocks of a token
// group are co-resident on XCD c for output write combining.
#define NTOK  32768
#define CIN   64
#define HDIM  128
#define O_CH  16
#define F2    16
#define SLOPE 0.01f
#define EPS   1e-5f

// LDS weight image (shorts). Rows 16B-aligned, 4-bank rotation/row.
#define SW0_STRIDE 72
#define SW1_STRIDE 136
#define SW2_STRIDE 136
#define SH_STRIDE  136
#define SW0_OFF 0                       // 128 x 72  = 9216
#define SW1_OFF 9216                    // 128 x 136 = 17408
#define SW2_OFF (9216 + 17408)          // 16  x 136 = 2176
#define WIMG_SHORTS 28800               // 57600 B per o-channel
#define SH_OFF  28800                   // 256 rows x 136 (16 waves x 16)
#define SH_ROWS 256
#define SMEM_SHORTS (28800 + SH_ROWS * SH_STRIDE)   // 63616 sh = 127232 B

// d_ws layout (bytes); ~0.93 MB total (ws proven >= 33.5 MB).
#define WIMG_OFF   0
#define WIMG_BYTES ((size_t)O_CH * WIMG_SHORTS * 2)          // 921600
#define B0F_OFF    WIMG_BYTES
#define B0F_BYTES  ((size_t)O_CH * HDIM * 4)
#define B1F_OFF    (B0F_OFF + B0F_BYTES)
#define B1F_BYTES  ((size_t)O_CH * HDIM * 4)
#define B2F_OFF    (B1F_OFF + B1F_BYTES)

typedef __attribute__((ext_vector_type(8))) short bf16x8;
typedef __attribute__((ext_vector_type(4))) short bf16x4;
typedef __attribute__((ext_vector_type(4))) float f32x4;

__device__ __forceinline__ unsigned short f2b(float f) {
  union { float f; unsigned int i; } v;
  v.f = f;
  unsigned int i = v.i;
  unsigned int r = (i + 0x7fffu + ((i >> 16) & 1u)) >> 16;  // RNE
  return (unsigned short)r;
}
// native float->bf16 (RNE); compiler packs adjacent pairs into
// v_cvt_pk_bf16_f32 on gfx950.
__device__ __forceinline__ short f2bn(float f) {
  union { __hip_bfloat16 h; short s; } v;
  v.h = __float2bfloat16(f);
  return v.s;
}
__device__ __forceinline__ float leaky(float t) {
  return fmaxf(t, SLOPE * t);   // == LeakyReLU for all finite t
}
__device__ __forceinline__ bf16x8 cvt8(const float* __restrict__ p) {
  float4 a = *(const float4*)p;
  float4 b = *(const float4*)(p + 4);
  bf16x8 r;
  r[0] = (short)f2b(a.x); r[1] = (short)f2b(a.y);
  r[2] = (short)f2b(a.z); r[3] = (short)f2b(a.w);
  r[4] = (short)f2b(b.x); r[5] = (short)f2b(b.y);
  r[6] = (short)f2b(b.z); r[7] = (short)f2b(b.w);
  return r;
}
__device__ __forceinline__ bf16x8 cvt8s(const float* __restrict__ p,
                                        const float* __restrict__ s) {
  bf16x8 r;
#pragma unroll
  for (int i = 0; i < 8; ++i) r[i] = (short)f2b(p[i] * s[i]);
  return r;
}

// leaky + LayerNorm on C-layout (col=token=lane&15, row=h). Lane holds 32 h
// of one token; butterfly xor 16,32 finishes the 128-sum. leaky written
// in-place into acc (saves 32 VGPRs vs a separate array); normalize is
// fma(v, rs, -mu*rs); bf16 pack via paired f2bn casts (native cvt_pk).
// Stores bf16 to LDS h[token][h] via ds_write_b64.
__device__ __forceinline__ void leaky_ln_store(
    f32x4* acc, unsigned short* __restrict__ sh,
    int row0, int lo16, int quad) {
  float s1 = 0.f, s2 = 0.f;
#pragma unroll
  for (int nt = 0; nt < 8; ++nt) {
#pragma unroll
    for (int r = 0; r < 4; ++r) {
      float t = leaky(acc[nt][r]);        // bias folded into C-init
      acc[nt][r] = t;
      s1 += t;
      s2 += t * t;
    }
  }
  s1 += __shfl_xor(s1, 16); s2 += __shfl_xor(s2, 16);
  s1 += __shfl_xor(s1, 32); s2 += __shfl_xor(s2, 32);
  float mu = s1 * (1.0f / 128.0f);
  float var = s2 * (1.0f / 128.0f) - mu * mu;
  float rs = rsqrtf(var + EPS);
  float nm = -mu * rs;                    // (v-mu)*rs == fma(v, rs, nm)
  unsigned short* dst = sh + (row0 + lo16) * SH_STRIDE + quad * 4;
#pragma unroll
  for (int nt = 0; nt < 8; ++nt) {
    bf16x4 p;
    p[0] = f2bn(fmaf(acc[nt][0], rs, nm));
    p[1] = f2bn(fmaf(acc[nt][1], rs, nm));
    p[2] = f2bn(fmaf(acc[nt][2], rs, nm));
    p[3] = f2bn(fmaf(acc[nt][3], rs, nm));
    *(bf16x4*)(dst + nt * 16) = p;
  }
}

// prep: 16 blocks build per-o bf16 weight images with gamma folded and
// folded bias vectors. [byte-identical to R8]
__global__ __launch_bounds__(256) void prep(
    const float* __restrict__ W0, const float* __restrict__ b0,
    const float* __restrict__ g0, const float* __restrict__ be0,
    const float* __restrict__ W1, const float* __restrict__ b1,
    const float* __restrict__ g1, const float* __restrict__ be1,
    const float* __restrict__ W2, const float* __restrict__ b2,
    unsigned short* __restrict__ wimg,
    float* __restrict__ b0f, float* __restrict__ b1f,
    float* __restrict__ b2f) {
  const int o = blockIdx.x, tid = threadIdx.x;
  __shared__ float sg0[HDIM], sbe0[HDIM], sg1[HDIM], sbe1[HDIM];
  if (tid < 128) {
    sg0[tid]  = g0 [o * HDIM + tid];
    sbe0[tid] = be0[o * HDIM + tid];
    sg1[tid]  = g1 [o * HDIM + tid];
    sbe1[tid] = be1[o * HDIM + tid];
  }
  __syncthreads();
  unsigned short* img = wimg + (size_t)o * WIMG_SHORTS;
  const float* w0 = W0 + (size_t)o * HDIM * CIN;
  for (int c = tid; c < (HDIM * CIN) / 8; c += 256) {
    int n = c >> 3, k8 = c & 7;
    *(bf16x8*)&img[SW0_OFF + n * SW0_STRIDE + k8 * 8] = cvt8(w0 + c * 8);
  }
  const float* w1 = W1 + (size_t)o * HDIM * HDIM;
  for (int c = tid; c < (HDIM * HDIM) / 8; c += 256) {
    int n = c >> 4, k8 = c & 15;
    *(bf16x8*)&img[SW1_OFF + n * SW1_STRIDE + k8 * 8] =
        cvt8s(w1 + c * 8, sg0 + k8 * 8);           // W1' = W1 * g0[k]
  }
  const float* w2 = W2 + (size_t)o * F2 * HDIM;
  for (int c = tid; c < (F2 * HDIM) / 8; c += 256) {
    int n = c >> 4, k8 = c & 15;
    *(bf16x8*)&img[SW2_OFF + n * SW2_STRIDE + k8 * 8] =
        cvt8s(w2 + c * 8, sg1 + k8 * 8);           // W2' = W2 * g1[k]
  }
  if (tid < 128) {
    b0f[o * HDIM + tid] = b0[o * HDIM + tid];
    float d = 0.f;
    const float* w1r = w1 + (size_t)tid * HDIM;
    for (int k = 0; k < HDIM; ++k) d += w1r[k] * sbe0[k];
    b1f[o * HDIM + tid] = b1[o * HDIM + tid] + d;  // b1' = b1 + W1*be0
  } else if (tid < 144) {
    int f = tid - 128;
    float d = 0.f;
    const float* w2r = w2 + (size_t)f * HDIM;
    for (int k = 0; k < HDIM; ++k) d += w2r[k] * sbe1[k];
    b2f[o * F2 + f] = b2[o * F2 + f] + d;          // b2' = b2 + W2*be1
  }
}

// film_main: block = one o x 1024 tokens (16 waves x 4 m-tiles), 1 block/CU
// (127.2 KB LDS) -> 4 waves/SIMD at <=128 VGPR (hence launch_bounds(.,4)).
// No cross-wave SH dependency (wave w owns rows [16w,16w+16)); the only
// barrier is after weight staging. bid = q*128 + o*8 + c: 16 o-blocks of
// token-group tg=q*8+c co-resident on XCD c -> output write combining.
__global__ __launch_bounds__(1024, 4) void film_main(
    const float* __restrict__ x,
    const unsigned short* __restrict__ wimg,
    const float* __restrict__ b0f, const float* __restrict__ b1f,
    const float* __restrict__ b2f,
    float* __restrict__ out) {
  __shared__ unsigned short smem[SMEM_SHORTS];
  const int tid = threadIdx.x;
  const int c   = blockIdx.x & 7;
  const int o   = (blockIdx.x >> 3) & 15;
  const int q   = blockIdx.x >> 7;
  const int tok0 = (q * 8 + c) * 1024;

  {  // stage prebuilt 57.6 KB bf16 weight image (contiguous copy)
    const bf16x8* src = (const bf16x8*)(wimg + (size_t)o * WIMG_SHORTS);
    for (int i = tid; i < WIMG_SHORTS / 8; i += 1024)
      *(bf16x8*)&smem[i * 8] = src[i];
  }

  const int lane = tid & 63;
  const int wave = tid >> 6;        // 0..15
  const int lo16 = lane & 15;
  const int quad = lane >> 4;
  const int row0 = wave * 16;

  // per-lane bias C-init fragments: h-dim = nt*16 + quad*4 + r
  f32x4 bias0[8], bias1[8];
#pragma unroll
  for (int nt = 0; nt < 8; ++nt) {
    bias0[nt] = *(const f32x4*)&b0f[o * HDIM + nt * 16 + quad * 4];
    bias1[nt] = *(const f32x4*)&b1f[o * HDIM + nt * 16 + quad * 4];
  }
  const f32x4 bias2 = *(const f32x4*)&b2f[o * F2 + quad * 4];
  __syncthreads();

  for (int mt = 0; mt < 4; ++mt) {
    const int trow = tok0 + wave * 64 + mt * 16;

    // ---- Layer 0: A=W0 (LDS), B=x tokens (fp32 -> bf16 in-register via
    //      native cvt; RNE, same numerics as the old xbf path)
    f32x4 acc[8];
#pragma unroll
    for (int nt = 0; nt < 8; ++nt) acc[nt] = bias0[nt];
    {
      const float* xr = x + (size_t)(trow + lo16) * CIN + quad * 8;
#pragma unroll
      for (int ks = 0; ks < 2; ++ks) {
        float4 xa = *(const float4*)(xr + ks * 32);
        float4 xb = *(const float4*)(xr + ks * 32 + 4);
        bf16x8 bx;
        bx[0] = f2bn(xa.x); bx[1] = f2bn(xa.y);
        bx[2] = f2bn(xa.z); bx[3] = f2bn(xa.w);
        bx[4] = f2bn(xb.x); bx[5] = f2bn(xb.y);
        bx[6] = f2bn(xb.z); bx[7] = f2bn(xb.w);
#pragma unroll
        for (int nt = 0; nt < 8; ++nt) {
          bf16x8 a = *(const bf16x8*)
              &smem[SW0_OFF + (nt * 16 + lo16) * SW0_STRIDE + ks * 32 + quad * 8];
          acc[nt] = __builtin_amdgcn_mfma_f32_16x16x32_bf16(a, bx, acc[nt], 0, 0, 0);
        }
      }
    }
    leaky_ln_store(acc, smem + SH_OFF, row0, lo16, quad);

    // ---- Layer 1: A=W1' (LDS), B=h
#pragma unroll
    for (int nt = 0; nt < 8; ++nt) acc[nt] = bias1[nt];
#pragma unroll
    for (int ks = 0; ks < 4; ++ks) {
      bf16x8 bh = *(const bf16x8*)
          &smem[SH_OFF + (row0 + lo16) * SH_STRIDE + ks * 32 + quad * 8];
#pragma unroll
      for (int nt = 0; nt < 8; ++nt) {
        bf16x8 a = *(const bf16x8*)
            &smem[SW1_OFF + (nt * 16 + lo16) * SW1_STRIDE + ks * 32 + quad * 8];
        acc[nt] = __builtin_amdgcn_mfma_f32_16x16x32_bf16(a, bh, acc[nt], 0, 0, 0);
      }
    }
    leaky_ln_store(acc, smem + SH_OFF, row0, lo16, quad);

    // ---- Layer 2: A=W2' (LDS), B=h -> C[col=token][row=f]
    f32x4 acc2 = bias2;
#pragma unroll
    for (int ks = 0; ks < 4; ++ks) {
      bf16x8 bh = *(const bf16x8*)
          &smem[SH_OFF + (row0 + lo16) * SH_STRIDE + ks * 32 + quad * 8];
      bf16x8 a = *(const bf16x8*)
          &smem[SW2_OFF + lo16 * SW2_STRIDE + ks * 32 + quad * 8];
      acc2 = __builtin_amdgcn_mfma_f32_16x16x32_bf16(a, bh, acc2, 0, 0, 0);
    }
    // direct fp32 out[tok][f][o]: token=trow+lo16, f=quad*4+r, o fixed.
    {
      const size_t tb = (size_t)(trow + lo16) * (F2 * O_CH);
#pragma unroll
      for (int r = 0; r < 4; ++r)
        out[tb + (quad * 4 + r) * O_CH + o] = leaky(acc2[r]);
    }
  }
}

extern "C" void kernel_launch(void* const* d_in, const int* in_sizes, int n_in,
                              void* d_out, int out_size, void* d_ws, size_t ws_size,
                              hipStream_t stream) {
  (void)in_sizes; (void)n_in; (void)out_size; (void)ws_size;
  const float* x   = (const float*)d_in[0];
  const float* W0  = (const float*)d_in[1];
  const float* b0  = (const float*)d_in[2];
  const float* g0  = (const float*)d_in[3];
  const float* be0 = (const float*)d_in[4];
  const float* W1  = (const float*)d_in[5];
  const float* b1  = (const float*)d_in[6];
  const float* g1  = (const float*)d_in[7];
  const float* be1 = (const float*)d_in[8];
  const float* W2  = (const float*)d_in[9];
  const float* b2  = (const float*)d_in[10];

  unsigned short* wimg = (unsigned short*)((char*)d_ws + WIMG_OFF);
  float* b0f = (float*)((char*)d_ws + B0F_OFF);
  float* b1f = (float*)((char*)d_ws + B1F_OFF);
  float* b2f = (float*)((char*)d_ws + B2F_OFF);

  prep<<<dim3(O_CH), dim3(256), 0, stream>>>(
      W0, b0, g0, be0, W1, b1, g1, be1, W2, b2, wimg, b0f, b1f, b2f);
  film_main<<<dim3(O_CH * (NTOK / 1024)), dim3(1024), 0, stream>>>(
      x, wimg, b0f, b1f, b2f, (float*)d_out);
}

// Round 6
// 151.126 us; speedup vs baseline: 1.2438x; 1.2438x over previous
//
#include <hip/hip_runtime.h>
#include <hip/hip_bf16.h>

// FiLM block, MI355X. I/O fp32; compute bf16 MFMA (A=weights, B=tokens,
// C col=token), fp32 accum. R12 = R11 resubmitted verbatim (R5 round died
// on a broker/container infra failure before compiling anything).
// R11 = R10 (passed, 110us) minus the scratch spills R10's counters
// exposed (FETCH 69MB / WRITE 92MB of spill traffic at VGPR_Count=64):
//  (1) amdgpu_waves_per_eu(4,4): launch_bounds' 2nd arg only LOWERS the
//      register budget; this attribute raises it (max 4 waves/EU -> the
//      allocator may use 512/4 = 128 VGPRs, the HW cap for 1024-thread
//      blocks anyway). LDS already caps occupancy at 4 waves/SIMD.
//  (2) bias0/bias1/bias2 moved from 68 persistent VGPRs to LDS (1088 B in
//      the 33KB spare); per-layer acc-init is 8 ds_read_b128 per mt.
//      Peak live drops to ~70 regs -> no spills even at a 64-reg budget.
// Numerics bit-identical to R10 (same bias floats, same f2bn/fmaf path).
// prep unchanged. XCD swizzle kept: bid = q*128 + o*8 + c.
#define NTOK  32768
#define CIN   64
#define HDIM  128
#define O_CH  16
#define F2    16
#define SLOPE 0.01f
#define EPS   1e-5f

// LDS weight image (shorts). Rows 16B-aligned, 4-bank rotation/row.
#define SW0_STRIDE 72
#define SW1_STRIDE 136
#define SW2_STRIDE 136
#define SH_STRIDE  136
#define SW0_OFF 0                       // 128 x 72  = 9216
#define SW1_OFF 9216                    // 128 x 136 = 17408
#define SW2_OFF (9216 + 17408)          // 16  x 136 = 2176
#define WIMG_SHORTS 28800               // 57600 B per o-channel
#define SH_OFF  28800                   // 256 rows x 136 (16 waves x 16)
#define SH_ROWS 256
#define SBIAS_OFF (SH_OFF + SH_ROWS * SH_STRIDE)    // shorts; 4B-aligned
#define SBIAS_FLOATS 272                 // b0'(128) b1'(128) b2'(16)
#define SMEM_SHORTS (SBIAS_OFF + SBIAS_FLOATS * 2)  // 128320 B total

// d_ws layout (bytes); ~0.93 MB total (ws proven >= 33.5 MB).
#define WIMG_OFF   0
#define WIMG_BYTES ((size_t)O_CH * WIMG_SHORTS * 2)          // 921600
#define B0F_OFF    WIMG_BYTES
#define B0F_BYTES  ((size_t)O_CH * HDIM * 4)
#define B1F_OFF    (B0F_OFF + B0F_BYTES)
#define B1F_BYTES  ((size_t)O_CH * HDIM * 4)
#define B2F_OFF    (B1F_OFF + B1F_BYTES)

typedef __attribute__((ext_vector_type(8))) short bf16x8;
typedef __attribute__((ext_vector_type(4))) short bf16x4;
typedef __attribute__((ext_vector_type(4))) float f32x4;

__device__ __forceinline__ unsigned short f2b(float f) {
  union { float f; unsigned int i; } v;
  v.f = f;
  unsigned int i = v.i;
  unsigned int r = (i + 0x7fffu + ((i >> 16) & 1u)) >> 16;  // RNE
  return (unsigned short)r;
}
// native float->bf16 (RNE); compiler packs adjacent pairs into
// v_cvt_pk_bf16_f32 on gfx950.
__device__ __forceinline__ short f2bn(float f) {
  union { __hip_bfloat16 h; short s; } v;
  v.h = __float2bfloat16(f);
  return v.s;
}
__device__ __forceinline__ float leaky(float t) {
  return fmaxf(t, SLOPE * t);   // == LeakyReLU for all finite t
}
__device__ __forceinline__ bf16x8 cvt8(const float* __restrict__ p) {
  float4 a = *(const float4*)p;
  float4 b = *(const float4*)(p + 4);
  bf16x8 r;
  r[0] = (short)f2b(a.x); r[1] = (short)f2b(a.y);
  r[2] = (short)f2b(a.z); r[3] = (short)f2b(a.w);
  r[4] = (short)f2b(b.x); r[5] = (short)f2b(b.y);
  r[6] = (short)f2b(b.z); r[7] = (short)f2b(b.w);
  return r;
}
__device__ __forceinline__ bf16x8 cvt8s(const float* __restrict__ p,
                                        const float* __restrict__ s) {
  bf16x8 r;
#pragma unroll
  for (int i = 0; i < 8; ++i) r[i] = (short)f2b(p[i] * s[i]);
  return r;
}

// leaky + LayerNorm on C-layout (col=token=lane&15, row=h). Lane holds 32 h
// of one token; butterfly xor 16,32 finishes the 128-sum. leaky written
// in-place into acc; normalize is fma(v, rs, -mu*rs); bf16 pack via paired
// f2bn casts (native cvt_pk). Stores bf16 to LDS h[token][h].
__device__ __forceinline__ void leaky_ln_store(
    f32x4* acc, unsigned short* __restrict__ sh,
    int row0, int lo16, int quad) {
  float s1 = 0.f, s2 = 0.f;
#pragma unroll
  for (int nt = 0; nt < 8; ++nt) {
#pragma unroll
    for (int r = 0; r < 4; ++r) {
      float t = leaky(acc[nt][r]);        // bias folded into C-init
      acc[nt][r] = t;
      s1 += t;
      s2 += t * t;
    }
  }
  s1 += __shfl_xor(s1, 16); s2 += __shfl_xor(s2, 16);
  s1 += __shfl_xor(s1, 32); s2 += __shfl_xor(s2, 32);
  float mu = s1 * (1.0f / 128.0f);
  float var = s2 * (1.0f / 128.0f) - mu * mu;
  float rs = rsqrtf(var + EPS);
  float nm = -mu * rs;                    // (v-mu)*rs == fma(v, rs, nm)
  unsigned short* dst = sh + (row0 + lo16) * SH_STRIDE + quad * 4;
#pragma unroll
  for (int nt = 0; nt < 8; ++nt) {
    bf16x4 p;
    p[0] = f2bn(fmaf(acc[nt][0], rs, nm));
    p[1] = f2bn(fmaf(acc[nt][1], rs, nm));
    p[2] = f2bn(fmaf(acc[nt][2], rs, nm));
    p[3] = f2bn(fmaf(acc[nt][3], rs, nm));
    *(bf16x4*)(dst + nt * 16) = p;
  }
}

// prep: 16 blocks build per-o bf16 weight images with gamma folded and
// folded bias vectors. [byte-identical to R8/R10]
__global__ __launch_bounds__(256) void prep(
    const float* __restrict__ W0, const float* __restrict__ b0,
    const float* __restrict__ g0, const float* __restrict__ be0,
    const float* __restrict__ W1, const float* __restrict__ b1,
    const float* __restrict__ g1, const float* __restrict__ be1,
    const float* __restrict__ W2, const float* __restrict__ b2,
    unsigned short* __restrict__ wimg,
    float* __restrict__ b0f, float* __restrict__ b1f,
    float* __restrict__ b2f) {
  const int o = blockIdx.x, tid = threadIdx.x;
  __shared__ float sg0[HDIM], sbe0[HDIM], sg1[HDIM], sbe1[HDIM];
  if (tid < 128) {
    sg0[tid]  = g0 [o * HDIM + tid];
    sbe0[tid] = be0[o * HDIM + tid];
    sg1[tid]  = g1 [o * HDIM + tid];
    sbe1[tid] = be1[o * HDIM + tid];
  }
  __syncthreads();
  unsigned short* img = wimg + (size_t)o * WIMG_SHORTS;
  const float* w0 = W0 + (size_t)o * HDIM * CIN;
  for (int c = tid; c < (HDIM * CIN) / 8; c += 256) {
    int n = c >> 3, k8 = c & 7;
    *(bf16x8*)&img[SW0_OFF + n * SW0_STRIDE + k8 * 8] = cvt8(w0 + c * 8);
  }
  const float* w1 = W1 + (size_t)o * HDIM * HDIM;
  for (int c = tid; c < (HDIM * HDIM) / 8; c += 256) {
    int n = c >> 4, k8 = c & 15;
    *(bf16x8*)&img[SW1_OFF + n * SW1_STRIDE + k8 * 8] =
        cvt8s(w1 + c * 8, sg0 + k8 * 8);           // W1' = W1 * g0[k]
  }
  const float* w2 = W2 + (size_t)o * F2 * HDIM;
  for (int c = tid; c < (F2 * HDIM) / 8; c += 256) {
    int n = c >> 4, k8 = c & 15;
    *(bf16x8*)&img[SW2_OFF + n * SW2_STRIDE + k8 * 8] =
        cvt8s(w2 + c * 8, sg1 + k8 * 8);           // W2' = W2 * g1[k]
  }
  if (tid < 128) {
    b0f[o * HDIM + tid] = b0[o * HDIM + tid];
    float d = 0.f;
    const float* w1r = w1 + (size_t)tid * HDIM;
    for (int k = 0; k < HDIM; ++k) d += w1r[k] * sbe0[k];
    b1f[o * HDIM + tid] = b1[o * HDIM + tid] + d;  // b1' = b1 + W1*be0
  } else if (tid < 144) {
    int f = tid - 128;
    float d = 0.f;
    const float* w2r = w2 + (size_t)f * HDIM;
    for (int k = 0; k < HDIM; ++k) d += w2r[k] * sbe1[k];
    b2f[o * F2 + f] = b2[o * F2 + f] + d;          // b2' = b2 + W2*be1
  }
}

// film_main: block = one o x 1024 tokens (16 waves x 4 m-tiles), 1 block/CU
// (128.3 KB LDS) -> 4 waves/SIMD; waves_per_eu(4,4) lets the allocator use
// up to 128 VGPRs (launch_bounds' 2nd arg can only lower the budget).
// Bias vectors live in LDS, not registers. No cross-wave SH dependency
// (wave w owns rows [16w,16w+16)); the only barrier is after staging.
// bid = q*128 + o*8 + c: 16 o-blocks of token-group tg=q*8+c co-resident
// on XCD c -> full-line write combining of the 4B/sector output stores.
__global__ __launch_bounds__(1024)
__attribute__((amdgpu_waves_per_eu(4, 4))) void film_main(
    const float* __restrict__ x,
    const unsigned short* __restrict__ wimg,
    const float* __restrict__ b0f, const float* __restrict__ b1f,
    const float* __restrict__ b2f,
    float* __restrict__ out) {
  __shared__ unsigned short smem[SMEM_SHORTS];
  const int tid = threadIdx.x;
  const int c   = blockIdx.x & 7;
  const int o   = (blockIdx.x >> 3) & 15;
  const int q   = blockIdx.x >> 7;
  const int tok0 = (q * 8 + c) * 1024;

  {  // stage prebuilt 57.6 KB bf16 weight image (contiguous copy)
    const bf16x8* src = (const bf16x8*)(wimg + (size_t)o * WIMG_SHORTS);
    for (int i = tid; i < WIMG_SHORTS / 8; i += 1024)
      *(bf16x8*)&smem[i * 8] = src[i];
  }
  // stage folded bias vectors (272 floats) into LDS
  float* sbias = (float*)&smem[SBIAS_OFF];
  if (tid < 128)      sbias[tid] = b0f[o * HDIM + tid];
  else if (tid < 256) sbias[tid] = b1f[o * HDIM + (tid - 128)];
  else if (tid < 272) sbias[tid] = b2f[o * F2 + (tid - 256)];

  const int lane = tid & 63;
  const int wave = tid >> 6;        // 0..15
  const int lo16 = lane & 15;
  const int quad = lane >> 4;
  const int row0 = wave * 16;
  const float* sb0 = sbias;
  const float* sb1 = sbias + HDIM;
  const float* sb2 = sbias + 2 * HDIM;
  __syncthreads();

  for (int mt = 0; mt < 4; ++mt) {
    const int trow = tok0 + wave * 64 + mt * 16;

    // ---- Layer 0: A=W0 (LDS), B=x tokens (fp32 -> bf16 in-register via
    //      native cvt; RNE, same numerics as the old xbf path)
    f32x4 acc[8];
#pragma unroll
    for (int nt = 0; nt < 8; ++nt)
      acc[nt] = *(const f32x4*)(sb0 + nt * 16 + quad * 4);
    {
      const float* xr = x + (size_t)(trow + lo16) * CIN + quad * 8;
#pragma unroll
      for (int ks = 0; ks < 2; ++ks) {
        float4 xa = *(const float4*)(xr + ks * 32);
        float4 xb = *(const float4*)(xr + ks * 32 + 4);
        bf16x8 bx;
        bx[0] = f2bn(xa.x); bx[1] = f2bn(xa.y);
        bx[2] = f2bn(xa.z); bx[3] = f2bn(xa.w);
        bx[4] = f2bn(xb.x); bx[5] = f2bn(xb.y);
        bx[6] = f2bn(xb.z); bx[7] = f2bn(xb.w);
#pragma unroll
        for (int nt = 0; nt < 8; ++nt) {
          bf16x8 a = *(const bf16x8*)
              &smem[SW0_OFF + (nt * 16 + lo16) * SW0_STRIDE + ks * 32 + quad * 8];
          acc[nt] = __builtin_amdgcn_mfma_f32_16x16x32_bf16(a, bx, acc[nt], 0, 0, 0);
        }
      }
    }
    leaky_ln_store(acc, smem + SH_OFF, row0, lo16, quad);

    // ---- Layer 1: A=W1' (LDS), B=h
#pragma unroll
    for (int nt = 0; nt < 8; ++nt)
      acc[nt] = *(const f32x4*)(sb1 + nt * 16 + quad * 4);
#pragma unroll
    for (int ks = 0; ks < 4; ++ks) {
      bf16x8 bh = *(const bf16x8*)
          &smem[SH_OFF + (row0 + lo16) * SH_STRIDE + ks * 32 + quad * 8];
#pragma unroll
      for (int nt = 0; nt < 8; ++nt) {
        bf16x8 a = *(const bf16x8*)
            &smem[SW1_OFF + (nt * 16 + lo16) * SW1_STRIDE + ks * 32 + quad * 8];
        acc[nt] = __builtin_amdgcn_mfma_f32_16x16x32_bf16(a, bh, acc[nt], 0, 0, 0);
      }
    }
    leaky_ln_store(acc, smem + SH_OFF, row0, lo16, quad);

    // ---- Layer 2: A=W2' (LDS), B=h -> C[col=token][row=f]
    f32x4 acc2 = *(const f32x4*)(sb2 + quad * 4);
#pragma unroll
    for (int ks = 0; ks < 4; ++ks) {
      bf16x8 bh = *(const bf16x8*)
          &smem[SH_OFF + (row0 + lo16) * SH_STRIDE + ks * 32 + quad * 8];
      bf16x8 a = *(const bf16x8*)
          &smem[SW2_OFF + lo16 * SW2_STRIDE + ks * 32 + quad * 8];
      acc2 = __builtin_amdgcn_mfma_f32_16x16x32_bf16(a, bh, acc2, 0, 0, 0);
    }
    // direct fp32 out[tok][f][o]: token=trow+lo16, f=quad*4+r, o fixed.
    {
      const size_t tb = (size_t)(trow + lo16) * (F2 * O_CH);
#pragma unroll
      for (int r = 0; r < 4; ++r)
        out[tb + (quad * 4 + r) * O_CH + o] = leaky(acc2[r]);
    }
  }
}

extern "C" void kernel_launch(void* const* d_in, const int* in_sizes, int n_in,
                              void* d_out, int out_size, void* d_ws, size_t ws_size,
                              hipStream_t stream) {
  (void)in_sizes; (void)n_in; (void)out_size; (void)ws_size;
  const float* x   = (const float*)d_in[0];
  const float* W0  = (const float*)d_in[1];
  const float* b0  = (const float*)d_in[2];
  const float* g0  = (const float*)d_in[3];
  const float* be0 = (const float*)d_in[4];
  const float* W1  = (const float*)d_in[5];
  const float* b1  = (const float*)d_in[6];
  const float* g1  = (const float*)d_in[7];
  const float* be1 = (const float*)d_in[8];
  const float* W2  = (const float*)d_in[9];
  const float* b2  = (const float*)d_in[10];

  unsigned short* wimg = (unsigned short*)((char*)d_ws + WIMG_OFF);
  float* b0f = (float*)((char*)d_ws + B0F_OFF);
  float* b1f = (float*)((char*)d_ws + B1F_OFF);
  float* b2f = (float*)((char*)d_ws + B2F_OFF);

  prep<<<dim3(O_CH), dim3(256), 0, stream>>>(
      W0, b0, g0, be0, W1, b1, g1, be1, W2, b2, wimg, b0f, b1f, b2f);
  film_main<<<dim3(O_CH * (NTOK / 1024)), dim3(1024), 0, stream>>>(
      x, wimg, b0f, b1f, b2f, (float*)d_out);
}

// Round 7
// 146.429 us; speedup vs baseline: 1.2837x; 1.0321x over previous
//
#include <hip/hip_runtime.h>
#include <hip/hip_bf16.h>

// FiLM block, MI355X. I/O fp32; compute bf16 MFMA (A=weights, B=tokens,
// C col=token), fp32 accum. R13 = R12 (passed, 75.4us film_main, spill-free
// at VGPR=64 with 64 regs of headroom) + two latency-chain cuts:
//  (1) striped LN reduction: 4+4 parallel accumulators + 3-add tree
//      (source order forced serial 32-deep FMA chains before; compiler
//      cannot reassociate without fast-math). Chain depth 32 -> 8.
//  (2) x software pipeline: mt+1's four float4 loaded right after mt's
//      conversion (uses the spare VGPRs R12's counters proved exist);
//      global-load latency moves off the front of each mt chain.
// Numerics: reassociated fp32 sums only (well within 0.059 threshold;
// measured absmax was 0.0156 with 3.8x headroom). All else identical.
// prep unchanged. XCD swizzle kept: bid = q*128 + o*8 + c.
#define NTOK  32768
#define CIN   64
#define HDIM  128
#define O_CH  16
#define F2    16
#define SLOPE 0.01f
#define EPS   1e-5f

// LDS weight image (shorts). Rows 16B-aligned, 4-bank rotation/row.
#define SW0_STRIDE 72
#define SW1_STRIDE 136
#define SW2_STRIDE 136
#define SH_STRIDE  136
#define SW0_OFF 0                       // 128 x 72  = 9216
#define SW1_OFF 9216                    // 128 x 136 = 17408
#define SW2_OFF (9216 + 17408)          // 16  x 136 = 2176
#define WIMG_SHORTS 28800               // 57600 B per o-channel
#define SH_OFF  28800                   // 256 rows x 136 (16 waves x 16)
#define SH_ROWS 256
#define SBIAS_OFF (SH_OFF + SH_ROWS * SH_STRIDE)    // shorts; 4B-aligned
#define SBIAS_FLOATS 272                 // b0'(128) b1'(128) b2'(16)
#define SMEM_SHORTS (SBIAS_OFF + SBIAS_FLOATS * 2)  // 128320 B total

// d_ws layout (bytes); ~0.93 MB total (ws proven >= 33.5 MB).
#define WIMG_OFF   0
#define WIMG_BYTES ((size_t)O_CH * WIMG_SHORTS * 2)          // 921600
#define B0F_OFF    WIMG_BYTES
#define B0F_BYTES  ((size_t)O_CH * HDIM * 4)
#define B1F_OFF    (B0F_OFF + B0F_BYTES)
#define B1F_BYTES  ((size_t)O_CH * HDIM * 4)
#define B2F_OFF    (B1F_OFF + B1F_BYTES)

typedef __attribute__((ext_vector_type(8))) short bf16x8;
typedef __attribute__((ext_vector_type(4))) short bf16x4;
typedef __attribute__((ext_vector_type(4))) float f32x4;

__device__ __forceinline__ unsigned short f2b(float f) {
  union { float f; unsigned int i; } v;
  v.f = f;
  unsigned int i = v.i;
  unsigned int r = (i + 0x7fffu + ((i >> 16) & 1u)) >> 16;  // RNE
  return (unsigned short)r;
}
// native float->bf16 (RNE); compiler packs adjacent pairs into
// v_cvt_pk_bf16_f32 on gfx950.  [validated R10/R12]
__device__ __forceinline__ short f2bn(float f) {
  union { __hip_bfloat16 h; short s; } v;
  v.h = __float2bfloat16(f);
  return v.s;
}
__device__ __forceinline__ float leaky(float t) {
  return fmaxf(t, SLOPE * t);   // == LeakyReLU for all finite t
}
__device__ __forceinline__ bf16x8 cvt8(const float* __restrict__ p) {
  float4 a = *(const float4*)p;
  float4 b = *(const float4*)(p + 4);
  bf16x8 r;
  r[0] = (short)f2b(a.x); r[1] = (short)f2b(a.y);
  r[2] = (short)f2b(a.z); r[3] = (short)f2b(a.w);
  r[4] = (short)f2b(b.x); r[5] = (short)f2b(b.y);
  r[6] = (short)f2b(b.z); r[7] = (short)f2b(b.w);
  return r;
}
__device__ __forceinline__ bf16x8 cvt8s(const float* __restrict__ p,
                                        const float* __restrict__ s) {
  bf16x8 r;
#pragma unroll
  for (int i = 0; i < 8; ++i) r[i] = (short)f2b(p[i] * s[i]);
  return r;
}

// leaky + LayerNorm on C-layout (col=token=lane&15, row=h). Lane holds 32 h
// of one token; butterfly xor 16,32 finishes the 128-sum. leaky written
// in-place into acc; sums use 4+4 parallel chains + tree (reassociation
// cuts dependent-FMA depth 32 -> 8); normalize is fma(v, rs, -mu*rs);
// bf16 pack via paired f2bn casts. Stores bf16 to LDS h[token][h].
__device__ __forceinline__ void leaky_ln_store(
    f32x4* acc, unsigned short* __restrict__ sh,
    int row0, int lo16, int quad) {
  float a0 = 0.f, a1 = 0.f, a2 = 0.f, a3 = 0.f;
  float c0 = 0.f, c1 = 0.f, c2 = 0.f, c3 = 0.f;
#pragma unroll
  for (int nt = 0; nt < 8; ++nt) {
    float t0 = leaky(acc[nt][0]);
    float t1 = leaky(acc[nt][1]);
    float t2 = leaky(acc[nt][2]);
    float t3 = leaky(acc[nt][3]);
    acc[nt][0] = t0; acc[nt][1] = t1; acc[nt][2] = t2; acc[nt][3] = t3;
    a0 += t0; a1 += t1; a2 += t2; a3 += t3;
    c0 = fmaf(t0, t0, c0); c1 = fmaf(t1, t1, c1);
    c2 = fmaf(t2, t2, c2); c3 = fmaf(t3, t3, c3);
  }
  float s1 = (a0 + a1) + (a2 + a3);
  float s2 = (c0 + c1) + (c2 + c3);
  s1 += __shfl_xor(s1, 16); s2 += __shfl_xor(s2, 16);
  s1 += __shfl_xor(s1, 32); s2 += __shfl_xor(s2, 32);
  float mu = s1 * (1.0f / 128.0f);
  float var = s2 * (1.0f / 128.0f) - mu * mu;
  float rs = rsqrtf(var + EPS);
  float nm = -mu * rs;                    // (v-mu)*rs == fma(v, rs, nm)
  unsigned short* dst = sh + (row0 + lo16) * SH_STRIDE + quad * 4;
#pragma unroll
  for (int nt = 0; nt < 8; ++nt) {
    bf16x4 p;
    p[0] = f2bn(fmaf(acc[nt][0], rs, nm));
    p[1] = f2bn(fmaf(acc[nt][1], rs, nm));
    p[2] = f2bn(fmaf(acc[nt][2], rs, nm));
    p[3] = f2bn(fmaf(acc[nt][3], rs, nm));
    *(bf16x4*)(dst + nt * 16) = p;
  }
}

// prep: 16 blocks build per-o bf16 weight images with gamma folded and
// folded bias vectors. [byte-identical to R8/R10/R12]
__global__ __launch_bounds__(256) void prep(
    const float* __restrict__ W0, const float* __restrict__ b0,
    const float* __restrict__ g0, const float* __restrict__ be0,
    const float* __restrict__ W1, const float* __restrict__ b1,
    const float* __restrict__ g1, const float* __restrict__ be1,
    const float* __restrict__ W2, const float* __restrict__ b2,
    unsigned short* __restrict__ wimg,
    float* __restrict__ b0f, float* __restrict__ b1f,
    float* __restrict__ b2f) {
  const int o = blockIdx.x, tid = threadIdx.x;
  __shared__ float sg0[HDIM], sbe0[HDIM], sg1[HDIM], sbe1[HDIM];
  if (tid < 128) {
    sg0[tid]  = g0 [o * HDIM + tid];
    sbe0[tid] = be0[o * HDIM + tid];
    sg1[tid]  = g1 [o * HDIM + tid];
    sbe1[tid] = be1[o * HDIM + tid];
  }
  __syncthreads();
  unsigned short* img = wimg + (size_t)o * WIMG_SHORTS;
  const float* w0 = W0 + (size_t)o * HDIM * CIN;
  for (int c = tid; c < (HDIM * CIN) / 8; c += 256) {
    int n = c >> 3, k8 = c & 7;
    *(bf16x8*)&img[SW0_OFF + n * SW0_STRIDE + k8 * 8] = cvt8(w0 + c * 8);
  }
  const float* w1 = W1 + (size_t)o * HDIM * HDIM;
  for (int c = tid; c < (HDIM * HDIM) / 8; c += 256) {
    int n = c >> 4, k8 = c & 15;
    *(bf16x8*)&img[SW1_OFF + n * SW1_STRIDE + k8 * 8] =
        cvt8s(w1 + c * 8, sg0 + k8 * 8);           // W1' = W1 * g0[k]
  }
  const float* w2 = W2 + (size_t)o * F2 * HDIM;
  for (int c = tid; c < (F2 * HDIM) / 8; c += 256) {
    int n = c >> 4, k8 = c & 15;
    *(bf16x8*)&img[SW2_OFF + n * SW2_STRIDE + k8 * 8] =
        cvt8s(w2 + c * 8, sg1 + k8 * 8);           // W2' = W2 * g1[k]
  }
  if (tid < 128) {
    b0f[o * HDIM + tid] = b0[o * HDIM + tid];
    float d = 0.f;
    const float* w1r = w1 + (size_t)tid * HDIM;
    for (int k = 0; k < HDIM; ++k) d += w1r[k] * sbe0[k];
    b1f[o * HDIM + tid] = b1[o * HDIM + tid] + d;  // b1' = b1 + W1*be0
  } else if (tid < 144) {
    int f = tid - 128;
    float d = 0.f;
    const float* w2r = w2 + (size_t)f * HDIM;
    for (int k = 0; k < HDIM; ++k) d += w2r[k] * sbe1[k];
    b2f[o * F2 + f] = b2[o * F2 + f] + d;          // b2' = b2 + W2*be1
  }
}

// film_main: block = one o x 1024 tokens (16 waves x 4 m-tiles), 1 block/CU
// (128.3 KB LDS) -> 4 waves/SIMD; waves_per_eu(4,4) budget = 128 VGPRs
// (R12 proved peak live fits with ~64 regs of headroom -> x-prefetch regs
// are free). Bias vectors in LDS. No cross-wave SH dependency; the only
// barrier is after staging. bid = q*128 + o*8 + c: 16 o-blocks of
// token-group tg=q*8+c co-resident on XCD c -> output write combining.
__global__ __launch_bounds__(1024)
__attribute__((amdgpu_waves_per_eu(4, 4))) void film_main(
    const float* __restrict__ x,
    const unsigned short* __restrict__ wimg,
    const float* __restrict__ b0f, const float* __restrict__ b1f,
    const float* __restrict__ b2f,
    float* __restrict__ out) {
  __shared__ unsigned short smem[SMEM_SHORTS];
  const int tid = threadIdx.x;
  const int c   = blockIdx.x & 7;
  const int o   = (blockIdx.x >> 3) & 15;
  const int q   = blockIdx.x >> 7;
  const int tok0 = (q * 8 + c) * 1024;

  {  // stage prebuilt 57.6 KB bf16 weight image (contiguous copy)
    const bf16x8* src = (const bf16x8*)(wimg + (size_t)o * WIMG_SHORTS);
    for (int i = tid; i < WIMG_SHORTS / 8; i += 1024)
      *(bf16x8*)&smem[i * 8] = src[i];
  }
  // stage folded bias vectors (272 floats) into LDS
  float* sbias = (float*)&smem[SBIAS_OFF];
  if (tid < 128)      sbias[tid] = b0f[o * HDIM + tid];
  else if (tid < 256) sbias[tid] = b1f[o * HDIM + (tid - 128)];
  else if (tid < 272) sbias[tid] = b2f[o * F2 + (tid - 256)];

  const int lane = tid & 63;
  const int wave = tid >> 6;        // 0..15
  const int lo16 = lane & 15;
  const int quad = lane >> 4;
  const int row0 = wave * 16;
  const float* sb0 = sbias;
  const float* sb1 = sbias + HDIM;
  const float* sb2 = sbias + 2 * HDIM;

  // x software pipeline: preload mt=0's 4 float4 before the barrier.
  const int tbase = tok0 + wave * 64;
  const float* xw = x + (size_t)(tbase + lo16) * CIN + quad * 8;
  float4 xa0 = *(const float4*)(xw);
  float4 xb0 = *(const float4*)(xw + 4);
  float4 xa1 = *(const float4*)(xw + 32);
  float4 xb1 = *(const float4*)(xw + 36);
  __syncthreads();

  for (int mt = 0; mt < 4; ++mt) {
    const int trow = tbase + mt * 16;

    // convert current x to bf16 B-fragments (RNE, native cvt)
    bf16x8 bx0, bx1;
    bx0[0] = f2bn(xa0.x); bx0[1] = f2bn(xa0.y);
    bx0[2] = f2bn(xa0.z); bx0[3] = f2bn(xa0.w);
    bx0[4] = f2bn(xb0.x); bx0[5] = f2bn(xb0.y);
    bx0[6] = f2bn(xb0.z); bx0[7] = f2bn(xb0.w);
    bx1[0] = f2bn(xa1.x); bx1[1] = f2bn(xa1.y);
    bx1[2] = f2bn(xa1.z); bx1[3] = f2bn(xa1.w);
    bx1[4] = f2bn(xb1.x); bx1[5] = f2bn(xb1.y);
    bx1[6] = f2bn(xb1.z); bx1[7] = f2bn(xb1.w);
    // issue next m-tile's loads now; latency hides under L0+LN0+L1
    if (mt < 3) {
      const float* xn = xw + (size_t)(mt + 1) * 16 * CIN;
      xa0 = *(const float4*)(xn);
      xb0 = *(const float4*)(xn + 4);
      xa1 = *(const float4*)(xn + 32);
      xb1 = *(const float4*)(xn + 36);
    }

    // ---- Layer 0: A=W0 (LDS), B=x tokens
    f32x4 acc[8];
#pragma unroll
    for (int nt = 0; nt < 8; ++nt)
      acc[nt] = *(const f32x4*)(sb0 + nt * 16 + quad * 4);
#pragma unroll
    for (int nt = 0; nt < 8; ++nt) {
      bf16x8 a = *(const bf16x8*)
          &smem[SW0_OFF + (nt * 16 + lo16) * SW0_STRIDE + quad * 8];
      acc[nt] = __builtin_amdgcn_mfma_f32_16x16x32_bf16(a, bx0, acc[nt], 0, 0, 0);
    }
#pragma unroll
    for (int nt = 0; nt < 8; ++nt) {
      bf16x8 a = *(const bf16x8*)
          &smem[SW0_OFF + (nt * 16 + lo16) * SW0_STRIDE + 32 + quad * 8];
      acc[nt] = __builtin_amdgcn_mfma_f32_16x16x32_bf16(a, bx1, acc[nt], 0, 0, 0);
    }
    leaky_ln_store(acc, smem + SH_OFF, row0, lo16, quad);

    // ---- Layer 1: A=W1' (LDS), B=h
#pragma unroll
    for (int nt = 0; nt < 8; ++nt)
      acc[nt] = *(const f32x4*)(sb1 + nt * 16 + quad * 4);
#pragma unroll
    for (int ks = 0; ks < 4; ++ks) {
      bf16x8 bh = *(const bf16x8*)
          &smem[SH_OFF + (row0 + lo16) * SH_STRIDE + ks * 32 + quad * 8];
#pragma unroll
      for (int nt = 0; nt < 8; ++nt) {
        bf16x8 a = *(const bf16x8*)
            &smem[SW1_OFF + (nt * 16 + lo16) * SW1_STRIDE + ks * 32 + quad * 8];
        acc[nt] = __builtin_amdgcn_mfma_f32_16x16x32_bf16(a, bh, acc[nt], 0, 0, 0);
      }
    }
    leaky_ln_store(acc, smem + SH_OFF, row0, lo16, quad);

    // ---- Layer 2: A=W2' (LDS), B=h -> C[col=token][row=f]
    f32x4 acc2 = *(const f32x4*)(sb2 + quad * 4);
#pragma unroll
    for (int ks = 0; ks < 4; ++ks) {
      bf16x8 bh = *(const bf16x8*)
          &smem[SH_OFF + (row0 + lo16) * SH_STRIDE + ks * 32 + quad * 8];
      bf16x8 a = *(const bf16x8*)
          &smem[SW2_OFF + lo16 * SW2_STRIDE + ks * 32 + quad * 8];
      acc2 = __builtin_amdgcn_mfma_f32_16x16x32_bf16(a, bh, acc2, 0, 0, 0);
    }
    // direct fp32 out[tok][f][o]: token=trow+lo16, f=quad*4+r, o fixed.
    {
      const size_t tb = (size_t)(trow + lo16) * (F2 * O_CH);
#pragma unroll
      for (int r = 0; r < 4; ++r)
        out[tb + (quad * 4 + r) * O_CH + o] = leaky(acc2[r]);
    }
  }
}

extern "C" void kernel_launch(void* const* d_in, const int* in_sizes, int n_in,
                              void* d_out, int out_size, void* d_ws, size_t ws_size,
                              hipStream_t stream) {
  (void)in_sizes; (void)n_in; (void)out_size; (void)ws_size;
  const float* x   = (const float*)d_in[0];
  const float* W0  = (const float*)d_in[1];
  const float* b0  = (const float*)d_in[2];
  const float* g0  = (const float*)d_in[3];
  const float* be0 = (const float*)d_in[4];
  const float* W1  = (const float*)d_in[5];
  const float* b1  = (const float*)d_in[6];
  const float* g1  = (const float*)d_in[7];
  const float* be1 = (const float*)d_in[8];
  const float* W2  = (const float*)d_in[9];
  const float* b2  = (const float*)d_in[10];

  unsigned short* wimg = (unsigned short*)((char*)d_ws + WIMG_OFF);
  float* b0f = (float*)((char*)d_ws + B0F_OFF);
  float* b1f = (float*)((char*)d_ws + B1F_OFF);
  float* b2f = (float*)((char*)d_ws + B2F_OFF);

  prep<<<dim3(O_CH), dim3(256), 0, stream>>>(
      W0, b0, g0, be0, W1, b1, g1, be1, W2, b2, wimg, b0f, b1f, b2f);
  film_main<<<dim3(O_CH * (NTOK / 1024)), dim3(1024), 0, stream>>>(
      x, wimg, b0f, b1f, b2f, (float*)d_out);
}